// Round 4
// baseline (171.138 us; speedup 1.0000x reference)
//
#include <hip/hip_runtime.h>

#define NB 8192
#define ANUM 5
#define OT_ELEMS (NB * 1024)   // floats of Ot, then Mt
#define EPSF 1e-10f

// Wave-local phase fence (R2-proven): full compiler memory barrier + drain of
// LDS/SMEM counters. Conservative but verified correct under graph replay.
#define WAVE_FENCE() asm volatile("s_waitcnt lgkmcnt(0)" ::: "memory")

// ---------------- Kernel 1: Cayley matrices M = (I-S)^-1 (I+S), stored transposed ----------------
__global__ void cayley_kernel(const float* __restrict__ Br,
                              const float* __restrict__ Bt,
                              const float* __restrict__ By,
                              float* __restrict__ MT_out) {
  __shared__ float A[32][33];
  __shared__ float R[32][33];
  const float* B = (blockIdx.x == 0) ? Br : (blockIdx.x == 1) ? Bt : By;
  const int t = threadIdx.x;
  const int i = t >> 5, j = t & 31;
  float Lij = (j < i) ? B[i - 1 + j] : 0.0f;
  float Lji = (i < j) ? B[j - 1 + i] : 0.0f;
  float S = Lij - Lji;
  float eye = (i == j) ? 1.0f : 0.0f;
  A[i][j] = eye - S;   // I - S
  R[i][j] = eye + S;   // I + S
  __syncthreads();
  for (int p = 0; p < 32; ++p) {
    float f = A[i][p] / A[p][p];
    __syncthreads();
    if (i != p) {
      A[i][j] -= f * A[p][j];
      R[i][j] -= f * R[p][j];
    }
    __syncthreads();
  }
  // slot0=MR^T, slot1=MT^T, slot2=MY^T :  MT_out[blk][j*32+i] = M[i][j]
  MT_out[blockIdx.x * 1024 + j * 32 + i] = R[i][j] / A[i][i];
}

// ---- mm_MQ: acc[r][c] += sum_k M[k][i0+r] * buf[k][j0+c]   (M stored-transposed, broadcast; buf swizzled)
__device__ __forceinline__ void mm_MQ(const float* __restrict__ M, const float* __restrict__ buf,
                                      int i0, int j0, float acc[4][4]) {
#pragma unroll
  for (int k = 0; k < 32; ++k) {
    const float4 a = *(const float4*)(M + k * 32 + i0);
    const float4 b = *(const float4*)(buf + k * 32 + (j0 ^ (k & 28)));
    acc[0][0] = fmaf(a.x, b.x, acc[0][0]);
    acc[0][1] = fmaf(a.x, b.y, acc[0][1]);
    acc[0][2] = fmaf(a.x, b.z, acc[0][2]);
    acc[0][3] = fmaf(a.x, b.w, acc[0][3]);
    acc[1][0] = fmaf(a.y, b.x, acc[1][0]);
    acc[1][1] = fmaf(a.y, b.y, acc[1][1]);
    acc[1][2] = fmaf(a.y, b.z, acc[1][2]);
    acc[1][3] = fmaf(a.y, b.w, acc[1][3]);
    acc[2][0] = fmaf(a.z, b.x, acc[2][0]);
    acc[2][1] = fmaf(a.z, b.y, acc[2][1]);
    acc[2][2] = fmaf(a.z, b.z, acc[2][2]);
    acc[2][3] = fmaf(a.z, b.w, acc[2][3]);
    acc[3][0] = fmaf(a.w, b.x, acc[3][0]);
    acc[3][1] = fmaf(a.w, b.y, acc[3][1]);
    acc[3][2] = fmaf(a.w, b.z, acc[3][2]);
    acc[3][3] = fmaf(a.w, b.w, acc[3][3]);
  }
}

// ---- mm_PM: acc[r][c] += sum_k buf[k][i0+r] * M[k][j0+c]   (buf swizzled; M broadcast)
__device__ __forceinline__ void mm_PM(const float* __restrict__ buf, const float* __restrict__ M,
                                      int i0, int j0, float acc[4][4]) {
#pragma unroll
  for (int k = 0; k < 32; ++k) {
    const float4 a = *(const float4*)(buf + k * 32 + (i0 ^ (k & 28)));
    const float4 b = *(const float4*)(M + k * 32 + j0);
    acc[0][0] = fmaf(a.x, b.x, acc[0][0]);
    acc[0][1] = fmaf(a.x, b.y, acc[0][1]);
    acc[0][2] = fmaf(a.x, b.z, acc[0][2]);
    acc[0][3] = fmaf(a.x, b.w, acc[0][3]);
    acc[1][0] = fmaf(a.y, b.x, acc[1][0]);
    acc[1][1] = fmaf(a.y, b.y, acc[1][1]);
    acc[1][2] = fmaf(a.y, b.z, acc[1][2]);
    acc[1][3] = fmaf(a.y, b.w, acc[1][3]);
    acc[2][0] = fmaf(a.z, b.x, acc[2][0]);
    acc[2][1] = fmaf(a.z, b.y, acc[2][1]);
    acc[2][2] = fmaf(a.z, b.z, acc[2][2]);
    acc[2][3] = fmaf(a.z, b.w, acc[2][3]);
    acc[3][0] = fmaf(a.w, b.x, acc[3][0]);
    acc[3][1] = fmaf(a.w, b.y, acc[3][1]);
    acc[3][2] = fmaf(a.w, b.z, acc[3][2]);
    acc[3][3] = fmaf(a.w, b.w, acc[3][3]);
  }
}

// ---------------- Kernel 2: main fused step. One wave per batch. ----------------
// U = sum wr[a]*M[a] (=Yt), V = sum wsn[a]*(1-al[a])*M[a], c = sum wsn[a]*al[a].
// C1: Rt = MR U MR^T ; Tt = (1-at)X + at*Rt
// C2: Phit = MT Tt MT^T ; Mt[a] = (1-al)*M[a](re-read) + al*Phit ; St = V + c*Phit
// C3: Ot = MY St MY^T
__global__ __launch_bounds__(256, 4) void spdsru_main(
    const float* __restrict__ X, const float* __restrict__ state,
    const float* __restrict__ WR, const float* __restrict__ Wt,
    const float* __restrict__ Wphi, const float* __restrict__ Ws,
    const float* __restrict__ Mws, float* __restrict__ out) {
  __shared__ float sM[3 * 1024];    // MR^T, MT^T, MY^T (row-major = M^T)
  __shared__ float sBuf[4][1024];   // per-wave swizzled operand buffer
  const int t = threadIdx.x;
  for (int idx = t; idx < 768; idx += 256)
    ((float4*)sM)[idx] = ((const float4*)Mws)[idx];

  // uniform scalars
  const float alpha[5] = {0.01f, 0.25f, 0.5f, 0.9f, 0.99f};
  float wr[5], va[5];
  float cP = 0.f;
  {
    float sR = 0.f, sS = 0.f, wq[5];
#pragma unroll
    for (int a = 0; a < 5; ++a) { float v = WR[a]; wr[a] = v * v; sR += v * v; }
#pragma unroll
    for (int a = 0; a < 5; ++a) { float v = Ws[a]; wq[a] = v * v; sS += v * v; }
    const float invR = 1.0f / (sR + EPSF), invS = 1.0f / (sS + EPSF);
#pragma unroll
    for (int a = 0; a < 5; ++a) {
      wr[a] *= invR;
      float w = wq[a] * invS;
      va[a] = w * (1.0f - alpha[a]);
      cP += w * alpha[a];
    }
  }
  const float wt2 = Wt[0] * Wt[0], wp2 = Wphi[0] * Wphi[0];
  const float at = wt2 / (wt2 + wp2 + EPSF);
  const float omat = 1.0f - at;

  const int wave = t >> 6, lane = t & 63;
  const int i0 = (lane >> 3) << 2;
  const int j0 = (lane & 7) << 2;
  const int batch = blockIdx.x * 4 + wave;
  float* buf = sBuf[wave];
  const float* MRb = sM;
  const float* MTb = sM + 1024;
  const float* MYb = sM + 2048;

  // load X (held in regs through C1), stream state -> U,V
  const float* xp = X + (size_t)batch * 1024;
  float4 x[4];
#pragma unroll
  for (int r = 0; r < 4; ++r) x[r] = *(const float4*)(xp + (i0 + r) * 32 + j0);

  const float* stp = state + (size_t)batch * (ANUM * 1024);
  float4 U[4], V[4];
#pragma unroll
  for (int r = 0; r < 4; ++r) { U[r] = make_float4(0.f, 0.f, 0.f, 0.f); V[r] = U[r]; }
#pragma unroll
  for (int a = 0; a < 5; ++a) {
#pragma unroll
    for (int r = 0; r < 4; ++r) {
      const float4 v = *(const float4*)(stp + a * 1024 + (i0 + r) * 32 + j0);
      U[r].x = fmaf(wr[a], v.x, U[r].x);  V[r].x = fmaf(va[a], v.x, V[r].x);
      U[r].y = fmaf(wr[a], v.y, U[r].y);  V[r].y = fmaf(va[a], v.y, V[r].y);
      U[r].z = fmaf(wr[a], v.z, U[r].z);  V[r].z = fmaf(va[a], v.z, V[r].z);
      U[r].w = fmaf(wr[a], v.w, U[r].w);  V[r].w = fmaf(va[a], v.w, V[r].w);
    }
  }

  __syncthreads();   // the ONLY block barrier: sM staging visible

  // ---- stage U (=Yt) ----
#pragma unroll
  for (int r = 0; r < 4; ++r)
    *(float4*)(buf + (i0 + r) * 32 + (j0 ^ i0)) = U[r];
  WAVE_FENCE();

  // ---- C1: t1 = MR*U ----
  float g[4][4] = {};
  mm_MQ(MRb, buf, i0, j0, g);
  WAVE_FENCE();
#pragma unroll
  for (int c = 0; c < 4; ++c)
    *(float4*)(buf + (j0 + c) * 32 + (i0 ^ j0)) = make_float4(g[0][c], g[1][c], g[2][c], g[3][c]);
  WAVE_FENCE();

  // ---- Rt = t1*MR^T ; Tt = (1-at)X + at*Rt -> buf ----
  float t2[4][4] = {};
  mm_PM(buf, MRb, i0, j0, t2);
  WAVE_FENCE();
#pragma unroll
  for (int r = 0; r < 4; ++r) {
    float4 v;
    v.x = omat * x[r].x + at * t2[r][0];
    v.y = omat * x[r].y + at * t2[r][1];
    v.z = omat * x[r].z + at * t2[r][2];
    v.w = omat * x[r].w + at * t2[r][3];
    *(float4*)(buf + (i0 + r) * 32 + (j0 ^ i0)) = v;
  }
  WAVE_FENCE();

  // ---- C2: u1 = MT*Tt ----
  float u1[4][4] = {};
  mm_MQ(MTb, buf, i0, j0, u1);
  WAVE_FENCE();
#pragma unroll
  for (int c = 0; c < 4; ++c)
    *(float4*)(buf + (j0 + c) * 32 + (i0 ^ j0)) = make_float4(u1[0][c], u1[1][c], u1[2][c], u1[3][c]);
  WAVE_FENCE();

  // ---- Phit = u1*MT^T ----
  float u2[4][4] = {};
  mm_PM(buf, MTb, i0, j0, u2);
  WAVE_FENCE();

  // ---- EMA: Mt[a] = (1-al)*M[a] + al*Phit (re-read state), St = V + cP*Phit -> buf ----
  float* outMt = out + OT_ELEMS + (size_t)batch * (ANUM * 1024);
#pragma unroll
  for (int a = 0; a < 5; ++a) {
    const float al = alpha[a], om = 1.0f - al;
#pragma unroll
    for (int r = 0; r < 4; ++r) {
      const float4 v = *(const float4*)(stp + a * 1024 + (i0 + r) * 32 + j0);
      float4 w;
      w.x = om * v.x + al * u2[r][0];
      w.y = om * v.y + al * u2[r][1];
      w.z = om * v.z + al * u2[r][2];
      w.w = om * v.w + al * u2[r][3];
      *(float4*)(outMt + a * 1024 + (i0 + r) * 32 + j0) = w;
    }
  }
#pragma unroll
  for (int r = 0; r < 4; ++r) {
    float4 s;
    s.x = fmaf(cP, u2[r][0], V[r].x);
    s.y = fmaf(cP, u2[r][1], V[r].y);
    s.z = fmaf(cP, u2[r][2], V[r].z);
    s.w = fmaf(cP, u2[r][3], V[r].w);
    *(float4*)(buf + (i0 + r) * 32 + (j0 ^ i0)) = s;
  }
  WAVE_FENCE();

  // ---- C3: v1 = MY*St ----
  float v1[4][4] = {};
  mm_MQ(MYb, buf, i0, j0, v1);
  WAVE_FENCE();
#pragma unroll
  for (int c = 0; c < 4; ++c)
    *(float4*)(buf + (j0 + c) * 32 + (i0 ^ j0)) = make_float4(v1[0][c], v1[1][c], v1[2][c], v1[3][c]);
  WAVE_FENCE();

  // ---- Ot = v1*MY^T ----
  float o[4][4] = {};
  mm_PM(buf, MYb, i0, j0, o);
  float* outOt = out + (size_t)batch * 1024;
#pragma unroll
  for (int r = 0; r < 4; ++r)
    *(float4*)(outOt + (i0 + r) * 32 + j0) = make_float4(o[r][0], o[r][1], o[r][2], o[r][3]);
}

extern "C" void kernel_launch(void* const* d_in, const int* in_sizes, int n_in,
                              void* d_out, int out_size, void* d_ws, size_t ws_size,
                              hipStream_t stream) {
  const float* X     = (const float*)d_in[0];
  const float* state = (const float*)d_in[1];
  const float* WR    = (const float*)d_in[2];
  const float* Wt    = (const float*)d_in[3];
  const float* Wphi  = (const float*)d_in[4];
  const float* Ws    = (const float*)d_in[5];
  const float* Br    = (const float*)d_in[6];
  const float* Bt    = (const float*)d_in[7];
  const float* By    = (const float*)d_in[8];
  float* mt_ws = (float*)d_ws;   // 3*1024 floats: MR^T, MT^T, MY^T
  float* outp = (float*)d_out;

  cayley_kernel<<<3, 1024, 0, stream>>>(Br, Bt, By, mt_ws);
  spdsru_main<<<NB / 4, 256, 0, stream>>>(X, state, WR, Wt, Wphi, Ws, mt_ws, outp);
}

// Round 5
// 104.942 us; speedup vs baseline: 1.6308x; 1.6308x over previous
//
#include <hip/hip_runtime.h>

#define NB 8192
#define OT_ELEMS (NB * 1024)   // floats of Ot, then Mt
#define EPSF 1e-10f

typedef __attribute__((ext_vector_type(4))) float f32x4;
typedef __attribute__((ext_vector_type(8))) short s16x8;   // 8 bf16 (4 VGPRs)

// Wave-local DS phase fence: compiler barrier + drain LDS queue (R2-proven).
#define WAVE_FENCE() asm volatile("s_waitcnt lgkmcnt(0)" ::: "memory")
#define MFMA_B16(A, B, C) __builtin_amdgcn_mfma_f32_16x16x32_bf16((A), (B), (C), 0, 0, 0)

// ---------------- Kernel 1: Cayley matrices M = (I-S)^-1 (I+S), stored ROW-major ----------------
__global__ void cayley_kernel(const float* __restrict__ Br,
                              const float* __restrict__ Bt,
                              const float* __restrict__ By,
                              float* __restrict__ M_out) {
  __shared__ float A[32][33];
  __shared__ float R[32][33];
  const float* B = (blockIdx.x == 0) ? Br : (blockIdx.x == 1) ? Bt : By;
  const int t = threadIdx.x;
  const int i = t >> 5, j = t & 31;
  float Lij = (j < i) ? B[i - 1 + j] : 0.0f;
  float Lji = (i < j) ? B[j - 1 + i] : 0.0f;
  float S = Lij - Lji;
  float eye = (i == j) ? 1.0f : 0.0f;
  A[i][j] = eye - S;   // I - S
  R[i][j] = eye + S;   // I + S
  __syncthreads();
  for (int p = 0; p < 32; ++p) {
    float f = A[i][p] / A[p][p];
    __syncthreads();
    if (i != p) {
      A[i][j] -= f * A[p][j];
      R[i][j] -= f * R[p][j];
    }
    __syncthreads();
  }
  // ROW-major: M_out[blk][i*32+j] = M[i][j]  (slot0=MR, slot1=MT, slot2=MY)
  M_out[blockIdx.x * 1024 + i * 32 + j] = R[i][j] / A[i][i];
}

// fp32 -> bf16 hi/lo split (hi = truncated top 16 bits; lo captures next 8 mantissa bits)
__device__ __forceinline__ void cvt_hilo8(const f32x4 f0, const f32x4 f1, s16x8& hi, s16x8& lo) {
  float f[8];
#pragma unroll
  for (int e = 0; e < 4; ++e) { f[e] = f0[e]; f[4 + e] = f1[e]; }
#pragma unroll
  for (int e = 0; e < 8; ++e) {
    unsigned u = __float_as_uint(f[e]);
    hi[e] = (short)(u >> 16);
    float ah = __uint_as_float(u & 0xffff0000u);
    lo[e] = (short)(__float_as_uint(f[e] - ah) >> 16);
  }
}

__device__ __forceinline__ void read_frag_lds(const float* sb, int off, s16x8& hi, s16x8& lo) {
  f32x4 f0 = *(const f32x4*)(sb + off);
  f32x4 f1 = *(const f32x4*)(sb + off + 4);
  cvt_hilo8(f0, f1, hi, lo);
}

// ---- one congruence  out = M * in * M^T  via 24 bf16 MFMAs (split-precision) ----
// in/out are C-layout tiles: in[ms][ns][r] = val[16*ms + 4*(lane>>4) + r][16*ns + (lane&15)]
// Mh/Ml: A-op fragments of M (lane&15+16s rows, (lane>>4)*8+e cols) — also valid as
// B-op fragments of M^T (identical register layout).
__device__ __forceinline__ void congruence(float* sb, int lane,
                                           const s16x8 (&Mh)[2], const s16x8 (&Ml)[2],
                                           const f32x4 (&in)[2][2], f32x4 (&out)[2][2]) {
  const int l15 = lane & 15, l4 = lane >> 4;
  // stage input COL-major (stride 36): addr = col*36 + row ; C-layout reg = 4 consecutive rows
#pragma unroll
  for (int ms = 0; ms < 2; ++ms)
#pragma unroll
    for (int ns = 0; ns < 2; ++ns)
      *(f32x4*)(sb + (16 * ns + l15) * 36 + 16 * ms + 4 * l4) = in[ms][ns];
  WAVE_FENCE();
  // B-frags of input: in[k][n], k = 8*l4+e consecutive, n = 16s+l15  -> col-major contiguous
  s16x8 Bh[2], Bl[2];
#pragma unroll
  for (int s = 0; s < 2; ++s)
    read_frag_lds(sb, (16 * s + l15) * 36 + 8 * l4, Bh[s], Bl[s]);
  WAVE_FENCE();
  // g = M * in
  f32x4 g[2][2];
#pragma unroll
  for (int ms = 0; ms < 2; ++ms)
#pragma unroll
    for (int ns = 0; ns < 2; ++ns) {
      f32x4 acc = {0.f, 0.f, 0.f, 0.f};
      acc = MFMA_B16(Ml[ms], Bh[ns], acc);
      acc = MFMA_B16(Mh[ms], Bl[ns], acc);
      acc = MFMA_B16(Mh[ms], Bh[ns], acc);
      g[ms][ns] = acc;
    }
  // stage g ROW-major (stride 36): addr = row*36 + col
#pragma unroll
  for (int ms = 0; ms < 2; ++ms)
#pragma unroll
    for (int ns = 0; ns < 2; ++ns)
#pragma unroll
      for (int r = 0; r < 4; ++r)
        sb[(16 * ms + 4 * l4 + r) * 36 + 16 * ns + l15] = g[ms][ns][r];
  WAVE_FENCE();
  // A-frags of g: g[row][k], row = 16s+l15, k = 8*l4+e consecutive -> row-major contiguous
  s16x8 Ah[2], Al[2];
#pragma unroll
  for (int s = 0; s < 2; ++s)
    read_frag_lds(sb, (16 * s + l15) * 36 + 8 * l4, Ah[s], Al[s]);
  WAVE_FENCE();
  // out = g * M^T   (B-op of M^T == A-op frags of M)
#pragma unroll
  for (int ms = 0; ms < 2; ++ms)
#pragma unroll
    for (int ns = 0; ns < 2; ++ns) {
      f32x4 acc = {0.f, 0.f, 0.f, 0.f};
      acc = MFMA_B16(Al[ms], Mh[ns], acc);
      acc = MFMA_B16(Ah[ms], Ml[ns], acc);
      acc = MFMA_B16(Ah[ms], Mh[ns], acc);
      out[ms][ns] = acc;
    }
}

// ---------------- Kernel 2: one wave per batch, 64-thread blocks, no __syncthreads ----------------
__global__ __launch_bounds__(64) void spdsru_main(
    const float* __restrict__ X, const float* __restrict__ state,
    const float* __restrict__ WR, const float* __restrict__ Wt,
    const float* __restrict__ Wphi, const float* __restrict__ Ws,
    const float* __restrict__ Mg, float* __restrict__ out) {
  __shared__ __align__(16) float sb[1152];
  const int lane = threadIdx.x;
  const int l15 = lane & 15, l4 = lane >> 4;
  const int batch = blockIdx.x;

  // M fragments from global (row-major M): M[16s+l15][8*l4+e], e=0..7 contiguous
  s16x8 Mh[3][2], Ml[3][2];
#pragma unroll
  for (int q = 0; q < 3; ++q)
#pragma unroll
    for (int s = 0; s < 2; ++s) {
      const float* p = Mg + q * 1024 + (16 * s + l15) * 32 + 8 * l4;
      cvt_hilo8(*(const f32x4*)p, *(const f32x4*)(p + 4), Mh[q][s], Ml[q][s]);
    }

  // X and state in C-layout (dword loads; 16 consecutive lanes = 64B segments)
  const float* xp = X + (size_t)batch * 1024;
  f32x4 x[2][2];
#pragma unroll
  for (int ms = 0; ms < 2; ++ms)
#pragma unroll
    for (int ns = 0; ns < 2; ++ns)
#pragma unroll
      for (int r = 0; r < 4; ++r)
        x[ms][ns][r] = xp[(16 * ms + 4 * l4 + r) * 32 + 16 * ns + l15];

  const float* stp = state + (size_t)batch * 5120;
  f32x4 m[5][2][2];
#pragma unroll
  for (int a = 0; a < 5; ++a)
#pragma unroll
    for (int ms = 0; ms < 2; ++ms)
#pragma unroll
      for (int ns = 0; ns < 2; ++ns)
#pragma unroll
        for (int r = 0; r < 4; ++r)
          m[a][ms][ns][r] = stp[a * 1024 + (16 * ms + 4 * l4 + r) * 32 + 16 * ns + l15];

  // uniform scalar weights
  const float alpha[5] = {0.01f, 0.25f, 0.5f, 0.9f, 0.99f};
  float wr[5], wsn[5];
  {
    float sR = 0.f, sS = 0.f;
#pragma unroll
    for (int a = 0; a < 5; ++a) { float v = WR[a]; wr[a] = v * v; sR += v * v; }
#pragma unroll
    for (int a = 0; a < 5; ++a) { float v = Ws[a]; wsn[a] = v * v; sS += v * v; }
    const float invR = 1.0f / (sR + EPSF), invS = 1.0f / (sS + EPSF);
#pragma unroll
    for (int a = 0; a < 5; ++a) { wr[a] *= invR; wsn[a] *= invS; }
  }
  const float wt2 = Wt[0] * Wt[0], wp2 = Wphi[0] * Wphi[0];
  const float at = wt2 / (wt2 + wp2 + EPSF);
  const float omat = 1.0f - at;

  // Yt = sum_a wr[a] * m[a]
  f32x4 U[2][2];
#pragma unroll
  for (int ms = 0; ms < 2; ++ms)
#pragma unroll
    for (int ns = 0; ns < 2; ++ns) {
      f32x4 u = wr[0] * m[0][ms][ns];
#pragma unroll
      for (int a = 1; a < 5; ++a) u += wr[a] * m[a][ms][ns];
      U[ms][ns] = u;
    }

  // C1: Rt = MR Yt MR^T
  f32x4 rt[2][2];
  congruence(sb, lane, Mh[0], Ml[0], U, rt);

  // Tt = (1-at)X + at*Rt
  f32x4 tt[2][2];
#pragma unroll
  for (int ms = 0; ms < 2; ++ms)
#pragma unroll
    for (int ns = 0; ns < 2; ++ns) tt[ms][ns] = omat * x[ms][ns] + at * rt[ms][ns];

  // C2: Phit = MT Tt MT^T
  f32x4 ph[2][2];
  congruence(sb, lane, Mh[1], Ml[1], tt, ph);

  // EMA write + St accumulation
  float* outMt = out + OT_ELEMS + (size_t)batch * 5120;
  f32x4 st[2][2];
#pragma unroll
  for (int ms = 0; ms < 2; ++ms)
#pragma unroll
    for (int ns = 0; ns < 2; ++ns) st[ms][ns] = f32x4{0.f, 0.f, 0.f, 0.f};
#pragma unroll
  for (int a = 0; a < 5; ++a) {
    const float al = alpha[a], om = 1.0f - al;
#pragma unroll
    for (int ms = 0; ms < 2; ++ms)
#pragma unroll
      for (int ns = 0; ns < 2; ++ns) {
        f32x4 mt = om * m[a][ms][ns] + al * ph[ms][ns];
        st[ms][ns] += wsn[a] * mt;
#pragma unroll
        for (int r = 0; r < 4; ++r)
          outMt[a * 1024 + (16 * ms + 4 * l4 + r) * 32 + 16 * ns + l15] = mt[r];
      }
  }

  // C3: Ot = MY St MY^T
  f32x4 ot[2][2];
  congruence(sb, lane, Mh[2], Ml[2], st, ot);

  float* outOt = out + (size_t)batch * 1024;
#pragma unroll
  for (int ms = 0; ms < 2; ++ms)
#pragma unroll
    for (int ns = 0; ns < 2; ++ns)
#pragma unroll
      for (int r = 0; r < 4; ++r)
        outOt[(16 * ms + 4 * l4 + r) * 32 + 16 * ns + l15] = ot[ms][ns][r];
}

extern "C" void kernel_launch(void* const* d_in, const int* in_sizes, int n_in,
                              void* d_out, int out_size, void* d_ws, size_t ws_size,
                              hipStream_t stream) {
  const float* X     = (const float*)d_in[0];
  const float* state = (const float*)d_in[1];
  const float* WR    = (const float*)d_in[2];
  const float* Wt    = (const float*)d_in[3];
  const float* Wphi  = (const float*)d_in[4];
  const float* Ws    = (const float*)d_in[5];
  const float* Br    = (const float*)d_in[6];
  const float* Bt    = (const float*)d_in[7];
  const float* By    = (const float*)d_in[8];
  float* m_ws = (float*)d_ws;   // 3*1024 floats: MR, MT, MY (row-major)
  float* outp = (float*)d_out;

  cayley_kernel<<<3, 1024, 0, stream>>>(Br, Bt, By, m_ws);
  spdsru_main<<<NB, 64, 0, stream>>>(X, state, WR, Wt, Wphi, Ws, m_ws, outp);
}

// Round 6
// 101.406 us; speedup vs baseline: 1.6877x; 1.0349x over previous
//
#include <hip/hip_runtime.h>

#define NB 8192
#define OT_ELEMS (NB * 1024)   // floats of Ot, then Mt
#define EPSF 1e-10f

typedef __attribute__((ext_vector_type(4))) float f32x4;
typedef __attribute__((ext_vector_type(8))) short s16x8;   // 8 bf16 (4 VGPRs)

// Wave-local DS phase fence (R2/R5-proven under graph replay).
#define WAVE_FENCE() asm volatile("s_waitcnt lgkmcnt(0)" ::: "memory")
#define MFMA_B16(A, B, C) __builtin_amdgcn_mfma_f32_16x16x32_bf16((A), (B), (C), 0, 0, 0)

// ---------------- Kernel 1: Cayley matrices M = (I-S)^-1 (I+S), stored ROW-major ----------------
__global__ void cayley_kernel(const float* __restrict__ Br,
                              const float* __restrict__ Bt,
                              const float* __restrict__ By,
                              float* __restrict__ M_out) {
  __shared__ float A[32][33];
  __shared__ float R[32][33];
  const float* B = (blockIdx.x == 0) ? Br : (blockIdx.x == 1) ? Bt : By;
  const int t = threadIdx.x;
  const int i = t >> 5, j = t & 31;
  float Lij = (j < i) ? B[i - 1 + j] : 0.0f;
  float Lji = (i < j) ? B[j - 1 + i] : 0.0f;
  float S = Lij - Lji;
  float eye = (i == j) ? 1.0f : 0.0f;
  A[i][j] = eye - S;   // I - S
  R[i][j] = eye + S;   // I + S
  __syncthreads();
  for (int p = 0; p < 32; ++p) {
    float f = A[i][p] / A[p][p];
    __syncthreads();
    if (i != p) {
      A[i][j] -= f * A[p][j];
      R[i][j] -= f * R[p][j];
    }
    __syncthreads();
  }
  // ROW-major: M_out[blk][i*32+j] = M[i][j]  (slot0=MR, slot1=MT, slot2=MY)
  M_out[blockIdx.x * 1024 + i * 32 + j] = R[i][j] / A[i][i];
}

// fp32 -> bf16 hi/lo split (hi = truncated top 16 bits; lo = next 8+ mantissa bits)
__device__ __forceinline__ void cvt_hilo8(const f32x4 f0, const f32x4 f1, s16x8& hi, s16x8& lo) {
  float f[8];
#pragma unroll
  for (int e = 0; e < 4; ++e) { f[e] = f0[e]; f[4 + e] = f1[e]; }
#pragma unroll
  for (int e = 0; e < 8; ++e) {
    unsigned u = __float_as_uint(f[e]);
    hi[e] = (short)(u >> 16);
    float ah = __uint_as_float(u & 0xffff0000u);
    lo[e] = (short)(__float_as_uint(f[e] - ah) >> 16);
  }
}

__device__ __forceinline__ void read_frag_lds(const float* sb, int off, s16x8& hi, s16x8& lo) {
  f32x4 f0 = *(const f32x4*)(sb + off);
  f32x4 f1 = *(const f32x4*)(sb + off + 4);
  cvt_hilo8(f0, f1, hi, lo);
}

// ---- one congruence  out = M * in * M^T, rowtile in / rowtile out ----
// rowtile: lane holds rows i0..i0+3 (i0=(lane>>3)*4) x cols j0..j0+3 (j0=(lane&7)*4),
//          in[r] = f32x4 over the 4 cols of row i0+r.   (dwordx4-friendly)
// Mh/Ml: A-op fragments of M (row = 16s+(lane&15), k = 8*(lane>>4)+e) — identical
// register layout serves as B-op fragments of M^T.  (R5-verified on HW.)
__device__ __forceinline__ void congruence_rt(float* sb, int lane,
                                              const s16x8 (&Mh)[2], const s16x8 (&Ml)[2],
                                              const f32x4 (&in)[4], f32x4 (&outr)[4]) {
  const int l15 = lane & 15, l4 = lane >> 4;
  const int i0 = (lane >> 3) << 2, j0 = (lane & 7) << 2;
  // stage `in` COL-major (stride 36): addr = col*36 + row; column vector via reg transpose
#pragma unroll
  for (int c = 0; c < 4; ++c) {
    f32x4 colv = {in[0][c], in[1][c], in[2][c], in[3][c]};
    *(f32x4*)(sb + (j0 + c) * 36 + i0) = colv;
  }
  WAVE_FENCE();
  // B-frags of `in`: in[k][col], 8 consecutive k at col-major addr
  s16x8 Bh[2], Bl[2];
#pragma unroll
  for (int s = 0; s < 2; ++s)
    read_frag_lds(sb, (16 * s + l15) * 36 + 8 * l4, Bh[s], Bl[s]);
  WAVE_FENCE();
  // g = M * in   (C-layout accumulators)
  f32x4 g[2][2];
#pragma unroll
  for (int ms = 0; ms < 2; ++ms)
#pragma unroll
    for (int ns = 0; ns < 2; ++ns) {
      f32x4 acc = {0.f, 0.f, 0.f, 0.f};
      acc = MFMA_B16(Ml[ms], Bh[ns], acc);
      acc = MFMA_B16(Mh[ms], Bl[ns], acc);
      acc = MFMA_B16(Mh[ms], Bh[ns], acc);
      g[ms][ns] = acc;
    }
  // stage g ROW-major (stride 36)
#pragma unroll
  for (int ms = 0; ms < 2; ++ms)
#pragma unroll
    for (int ns = 0; ns < 2; ++ns)
#pragma unroll
      for (int r = 0; r < 4; ++r)
        sb[(16 * ms + 4 * l4 + r) * 36 + 16 * ns + l15] = g[ms][ns][r];
  WAVE_FENCE();
  // A-frags of g: row-major contiguous k
  s16x8 Ah[2], Al[2];
#pragma unroll
  for (int s = 0; s < 2; ++s)
    read_frag_lds(sb, (16 * s + l15) * 36 + 8 * l4, Ah[s], Al[s]);
  WAVE_FENCE();
  // o = g * M^T
  f32x4 o[2][2];
#pragma unroll
  for (int ms = 0; ms < 2; ++ms)
#pragma unroll
    for (int ns = 0; ns < 2; ++ns) {
      f32x4 acc = {0.f, 0.f, 0.f, 0.f};
      acc = MFMA_B16(Al[ms], Mh[ns], acc);
      acc = MFMA_B16(Ah[ms], Ml[ns], acc);
      acc = MFMA_B16(Ah[ms], Mh[ns], acc);
      o[ms][ns] = acc;
    }
  // convert o: C-layout -> rowtile through LDS (row-major stage, f32x4 read)
#pragma unroll
  for (int ms = 0; ms < 2; ++ms)
#pragma unroll
    for (int ns = 0; ns < 2; ++ns)
#pragma unroll
      for (int r = 0; r < 4; ++r)
        sb[(16 * ms + 4 * l4 + r) * 36 + 16 * ns + l15] = o[ms][ns][r];
  WAVE_FENCE();
#pragma unroll
  for (int r = 0; r < 4; ++r)
    outr[r] = *(const f32x4*)(sb + (i0 + r) * 36 + j0);
  WAVE_FENCE();
}

// ---------------- Kernel 2: one wave per batch, 64-thread blocks, no __syncthreads ----------------
// U = sum wr[a]*M[a], V = sum wsn[a]*(1-al[a])*M[a], cP = sum wsn[a]*al[a].
// Rt = MR U MR^T ; Tt = (1-at)X + at*Rt ; Phit = MT Tt MT^T ;
// Mt[a] = (1-al)*M[a](L2 re-read) + al*Phit ; St = V + cP*Phit ; Ot = MY St MY^T.
__global__ __launch_bounds__(64) void spdsru_main(
    const float* __restrict__ X, const float* __restrict__ state,
    const float* __restrict__ WR, const float* __restrict__ Wt,
    const float* __restrict__ Wphi, const float* __restrict__ Ws,
    const float* __restrict__ Mg, float* __restrict__ out) {
  __shared__ __align__(16) float sb[1152];
  const int lane = threadIdx.x;
  const int l15 = lane & 15, l4 = lane >> 4;
  const int i0 = (lane >> 3) << 2, j0 = (lane & 7) << 2;
  const int batch = blockIdx.x;

  // M fragments from global (row-major M)
  s16x8 Mh[3][2], Ml[3][2];
#pragma unroll
  for (int q = 0; q < 3; ++q)
#pragma unroll
    for (int s = 0; s < 2; ++s) {
      const float* p = Mg + q * 1024 + (16 * s + l15) * 32 + 8 * l4;
      cvt_hilo8(*(const f32x4*)p, *(const f32x4*)(p + 4), Mh[q][s], Ml[q][s]);
    }

  // uniform scalar weights
  const float alpha[5] = {0.01f, 0.25f, 0.5f, 0.9f, 0.99f};
  float wr[5], va[5];
  float cP = 0.f;
  {
    float sR = 0.f, sS = 0.f, wq[5];
#pragma unroll
    for (int a = 0; a < 5; ++a) { float v = WR[a]; wr[a] = v * v; sR += v * v; }
#pragma unroll
    for (int a = 0; a < 5; ++a) { float v = Ws[a]; wq[a] = v * v; sS += v * v; }
    const float invR = 1.0f / (sR + EPSF), invS = 1.0f / (sS + EPSF);
#pragma unroll
    for (int a = 0; a < 5; ++a) {
      wr[a] *= invR;
      float w = wq[a] * invS;
      va[a] = w * (1.0f - alpha[a]);
      cP += w * alpha[a];
    }
  }
  const float wt2 = Wt[0] * Wt[0], wp2 = Wphi[0] * Wphi[0];
  const float at = wt2 / (wt2 + wp2 + EPSF);
  const float omat = 1.0f - at;

  // X in rowtile (dwordx4)
  const float* xp = X + (size_t)batch * 1024;
  f32x4 x[4];
#pragma unroll
  for (int r = 0; r < 4; ++r) x[r] = *(const f32x4*)(xp + (i0 + r) * 32 + j0);

  // first state pass: fold into U, V (dwordx4, state read once here)
  const float* stp = state + (size_t)batch * 5120;
  f32x4 U[4], V[4];
#pragma unroll
  for (int r = 0; r < 4; ++r) { U[r] = f32x4{0.f, 0.f, 0.f, 0.f}; V[r] = U[r]; }
#pragma unroll
  for (int a = 0; a < 5; ++a)
#pragma unroll
    for (int r = 0; r < 4; ++r) {
      const f32x4 v = *(const f32x4*)(stp + a * 1024 + (i0 + r) * 32 + j0);
      U[r] += wr[a] * v;
      V[r] += va[a] * v;
    }

  // C1: Rt = MR U MR^T ; Tt = (1-at)X + at*Rt
  f32x4 rt[4];
  congruence_rt(sb, lane, Mh[0], Ml[0], U, rt);
  f32x4 tt[4];
#pragma unroll
  for (int r = 0; r < 4; ++r) tt[r] = omat * x[r] + at * rt[r];

  // C2: Phit = MT Tt MT^T
  f32x4 ph[4];
  congruence_rt(sb, lane, Mh[1], Ml[1], tt, ph);

  // EMA: re-read state (L2-hot), write Mt (dwordx4)
  float* outMt = out + OT_ELEMS + (size_t)batch * 5120;
#pragma unroll
  for (int a = 0; a < 5; ++a) {
    const float al = alpha[a], om = 1.0f - al;
#pragma unroll
    for (int r = 0; r < 4; ++r) {
      const f32x4 v = *(const f32x4*)(stp + a * 1024 + (i0 + r) * 32 + j0);
      f32x4 w = om * v + al * ph[r];
      *(f32x4*)(outMt + a * 1024 + (i0 + r) * 32 + j0) = w;
    }
  }

  // St = V + cP*Phit ; C3: Ot = MY St MY^T
  f32x4 st[4];
#pragma unroll
  for (int r = 0; r < 4; ++r) st[r] = V[r] + cP * ph[r];
  f32x4 ot[4];
  congruence_rt(sb, lane, Mh[2], Ml[2], st, ot);

  float* outOt = out + (size_t)batch * 1024;
#pragma unroll
  for (int r = 0; r < 4; ++r)
    *(f32x4*)(outOt + (i0 + r) * 32 + j0) = ot[r];
}

extern "C" void kernel_launch(void* const* d_in, const int* in_sizes, int n_in,
                              void* d_out, int out_size, void* d_ws, size_t ws_size,
                              hipStream_t stream) {
  const float* X     = (const float*)d_in[0];
  const float* state = (const float*)d_in[1];
  const float* WR    = (const float*)d_in[2];
  const float* Wt    = (const float*)d_in[3];
  const float* Wphi  = (const float*)d_in[4];
  const float* Ws    = (const float*)d_in[5];
  const float* Br    = (const float*)d_in[6];
  const float* Bt    = (const float*)d_in[7];
  const float* By    = (const float*)d_in[8];
  float* m_ws = (float*)d_ws;   // 3*1024 floats: MR, MT, MY (row-major)
  float* outp = (float*)d_out;

  cayley_kernel<<<3, 1024, 0, stream>>>(Br, Bt, By, m_ws);
  spdsru_main<<<NB, 64, 0, stream>>>(X, state, WR, Wt, Wphi, Ws, m_ws, outp);
}